// Round 1
// baseline (145.420 us; speedup 1.0000x reference)
//
#include <hip/hip_runtime.h>
#include <math.h>

// Problem constants
#define NF 128   // n_features / out_dim
#define HH 256   // hidden width
#define BB 16    // batch

// ws layout (float offsets)
static constexpr int OFF_W1T  = 0;            // [256][128]
static constexpr int OFF_W2T  = 32768;        // [128][256]
static constexpr int OFF_S    = 65536;        // [256][256]
static constexpr int OFF_Q    = 131072;       // [256][256]
static constexpr int OFF_D    = 196608;       // [16][256]
static constexpr int OFF_C    = 200704;       // [16][256]
static constexpr int OFF_UV   = 204800;       // [16][256]
static constexpr int OFF_AV   = 208896;       // [16][256]
static constexpr int OFF_VN   = 212992;       // [16]
static constexpr int OFF_PART = 213008;       // [16][36]
static constexpr int OFF_PT   = 213760;       // [16][128][256]  (PT[b][j][m] = P[b][m][j])
// total = 738048 floats = ~2.95 MB

// ---------------- transpose: out[c*R + r] = in[r*C + c] ----------------
__global__ __launch_bounds__(256) void k_transpose(const float* __restrict__ in,
                                                   float* __restrict__ out,
                                                   int R, int C) {
    __shared__ float tile[32][33];
    int c0 = blockIdx.x * 32, r0 = blockIdx.y * 32;
    int tx = threadIdx.x & 31, ty = threadIdx.x >> 5;  // ty in 0..7
    for (int i = 0; i < 32; i += 8)
        tile[ty + i][tx] = in[(r0 + ty + i) * C + c0 + tx];
    __syncthreads();
    for (int i = 0; i < 32; i += 8)
        out[(c0 + ty + i) * R + r0 + tx] = tile[tx][ty + i];
}

// ---------------- gram over rows: G[m,n] = sum_k X[m,k]X[n,k], X: [256][128] ----------------
__global__ __launch_bounds__(256) void k_gram(const float* __restrict__ X,
                                              float* __restrict__ G) {
    __shared__ __align__(16) float Xi[32][34];
    __shared__ __align__(16) float Xj[32][34];
    int m0 = blockIdx.y * 32, n0 = blockIdx.x * 32;
    int tid = threadIdx.x;
    int lx = tid & 31, lr = tid >> 5;
    int tx = tid & 15, ty = tid >> 4;
    float a00 = 0, a01 = 0, a10 = 0, a11 = 0;
    for (int kc = 0; kc < 128; kc += 32) {
        for (int i = 0; i < 32; i += 8) {
            Xi[lx][lr + i] = X[(m0 + lr + i) * 128 + kc + lx];
            Xj[lx][lr + i] = X[(n0 + lr + i) * 128 + kc + lx];
        }
        __syncthreads();
        for (int k = 0; k < 32; ++k) {
            float2 a = *(const float2*)&Xi[k][2 * ty];
            float2 b = *(const float2*)&Xj[k][2 * tx];
            a00 += a.x * b.x; a01 += a.x * b.y;
            a10 += a.y * b.x; a11 += a.y * b.y;
        }
        __syncthreads();
    }
    int m = m0 + 2 * ty, n = n0 + 2 * tx;
    G[m * 256 + n]           = a00;
    G[m * 256 + n + 1]       = a01;
    G[(m + 1) * 256 + n]     = a10;
    G[(m + 1) * 256 + n + 1] = a11;
}

// ---------------- per-sample prep ----------------
// x = x0 + t(x1-x0) + 4t(1-t)*dev; h = xW1+b1; z=tanh(h); d=1-z^2; c=-2 z d
// uv_m = sum_k W1[k,m] v_k ; av_m = sum_j W2[m,j] v_j ; vnorm = ||v||
// also writes out rows 0..15 (= dev_velocity)
__global__ __launch_bounds__(256) void k_prep(const float* __restrict__ tptr,
                                              const float* __restrict__ state,
                                              const float* __restrict__ x0,
                                              const float* __restrict__ x1,
                                              const float* __restrict__ W1,
                                              const float* __restrict__ b1,
                                              float* __restrict__ ws,
                                              float* __restrict__ out) {
    int b = blockIdx.x;
    int tid = threadIdx.x;
    __shared__ float xs[128], vs[128], red[128];
    float t = tptr[0];
    float w = 4.f * t * (1.f - t);
    if (tid < 128) {
        float dev = state[b * 128 + tid];
        float v   = state[(16 + b) * 128 + tid];
        float xv  = x0[b * 128 + tid] + t * (x1[b * 128 + tid] - x0[b * 128 + tid]) + w * dev;
        xs[tid] = xv;
        vs[tid] = v;
        out[b * 128 + tid] = v;       // first-half output = dev_velocity
        red[tid] = v * v;
    }
    __syncthreads();
    // vnorm tree reduce
    for (int s = 64; s > 0; s >>= 1) {
        if (tid < s) red[tid] += red[tid + s];
        __syncthreads();
    }
    if (tid == 0) ws[OFF_VN + b] = sqrtf(red[0]);

    int m = tid;  // 0..255
    float h = b1[m], uvm = 0.f;
    for (int k = 0; k < 128; ++k) {
        float wv = W1[k * 256 + m];        // coalesced
        h   += xs[k] * wv;
        uvm += vs[k] * wv;
    }
    float z  = tanhf(h);
    float dd = 1.f - z * z;
    float cc = -2.f * z * dd;
    const float* W2T = ws + OFF_W2T;
    float avm = 0.f;
    for (int j = 0; j < 128; ++j)
        avm += W2T[j * 256 + m] * vs[j];   // coalesced
    ws[OFF_D  + b * 256 + m] = dd;
    ws[OFF_C  + b * 256 + m] = cc;
    ws[OFF_UV + b * 256 + m] = uvm;
    ws[OFF_AV + b * 256 + m] = avm;
}

// ---------------- P = S * diag(d) * W2, stored transposed: PT[b][j][m] ----------------
__global__ __launch_bounds__(256) void k_pmat(const float* __restrict__ Smat,
                                              const float* __restrict__ dall,
                                              const float* __restrict__ W2,
                                              float* __restrict__ PT) {
    int b = blockIdx.z, mt = blockIdx.y, jt = blockIdx.x;
    int m0 = mt * 32, j0 = jt * 32;
    const float* dvec = dall + b * 256;
    __shared__ __align__(16) float ST[32][34];  // ST[k][m-local]
    __shared__ __align__(16) float YT[32][34];  // YT[k][j-local]
    int tid = threadIdx.x;
    int lx = tid & 31, lr = tid >> 5;
    int tx = tid & 15, ty = tid >> 4;
    float a00 = 0, a01 = 0, a10 = 0, a11 = 0;
    for (int nc = 0; nc < 256; nc += 32) {
        for (int i = 0; i < 32; i += 8) {
            ST[lx][lr + i] = Smat[(m0 + lr + i) * 256 + nc + lx];
            int n = nc + lr + i;
            YT[lr + i][lx] = dvec[n] * W2[n * 128 + j0 + lx];
        }
        __syncthreads();
        for (int k = 0; k < 32; ++k) {
            float2 a  = *(const float2*)&ST[k][2 * ty];
            float2 bb = *(const float2*)&YT[k][2 * tx];
            a00 += a.x * bb.x; a01 += a.x * bb.y;
            a10 += a.y * bb.x; a11 += a.y * bb.y;
        }
        __syncthreads();
    }
    float* ptb = PT + b * 32768;
    int m = m0 + 2 * ty, j = j0 + 2 * tx;
    ptb[j * 256 + m]           = a00;
    ptb[(j + 1) * 256 + m]     = a01;
    ptb[j * 256 + m + 1]       = a10;
    ptb[(j + 1) * 256 + m + 1] = a11;
}

// ---------------- fused Frobenius-norm accumulation ----------------
// partial[b][tile] = sum over 32x32 (m,m') tile of c_m c_m' S[m,m'] *
//                    ( Q[m,m']*R[m,m'] + M[m,m']*M[m',m] )
// R = P P^T, M = P W2^T; triangular tiles (ti<=tj), off-diag scaled x2.
__global__ __launch_bounds__(256) void k_fnorm(const float* __restrict__ PT,
                                               const float* __restrict__ W2T,
                                               const float* __restrict__ Smat,
                                               const float* __restrict__ Qmat,
                                               const float* __restrict__ call,
                                               float* __restrict__ partial) {
    __shared__ __align__(16) float lds[16384];  // 64 KB
    float* PiT = lds;              // [128][32]
    float* PjT = lds + 4096;
    float* WiT = lds + 8192;
    float* WjT = lds + 12288;
    int b = blockIdx.y;
    int idx = blockIdx.x;
    int tj = 0;
    while ((tj + 1) * (tj + 2) / 2 <= idx) ++tj;
    int ti = idx - tj * (tj + 1) / 2;      // ti <= tj
    int mi0 = ti * 32, mj0 = tj * 32;
    int tid = threadIdx.x;
    int lm = tid & 31, ljr = tid >> 5;
    const float* ptb = PT + b * 32768;
    for (int j = ljr; j < 128; j += 8) {
        PiT[j * 32 + lm] = ptb[j * 256 + mi0 + lm];
        PjT[j * 32 + lm] = ptb[j * 256 + mj0 + lm];
        WiT[j * 32 + lm] = W2T[j * 256 + mi0 + lm];
        WjT[j * 32 + lm] = W2T[j * 256 + mj0 + lm];
    }
    __syncthreads();
    int tx = tid & 15, ty = tid >> 4;
    float r00=0,r01=0,r10=0,r11=0;
    float f00=0,f01=0,f10=0,f11=0;   // M[m, m']
    float g00=0,g01=0,g10=0,g11=0;   // M[m', m]
    for (int j = 0; j < 128; ++j) {
        float2 pi = *(const float2*)&PiT[j * 32 + 2 * ty];
        float2 pj = *(const float2*)&PjT[j * 32 + 2 * tx];
        float2 wi = *(const float2*)&WiT[j * 32 + 2 * ty];
        float2 wj = *(const float2*)&WjT[j * 32 + 2 * tx];
        r00 += pi.x * pj.x; r01 += pi.x * pj.y; r10 += pi.y * pj.x; r11 += pi.y * pj.y;
        f00 += pi.x * wj.x; f01 += pi.x * wj.y; f10 += pi.y * wj.x; f11 += pi.y * wj.y;
        g00 += pj.x * wi.x; g01 += pj.y * wi.x; g10 += pj.x * wi.y; g11 += pj.y * wi.y;
    }
    const float* cb = call + b * 256;
    int ma = mi0 + 2 * ty, mp = mj0 + 2 * tx;
    float c0 = cb[ma], c1 = cb[ma + 1], e0 = cb[mp], e1 = cb[mp + 1];
    float sum = 0.f;
    sum += c0 * e0 * Smat[ma * 256 + mp]           * (Qmat[ma * 256 + mp]           * r00 + f00 * g00);
    sum += c0 * e1 * Smat[ma * 256 + mp + 1]       * (Qmat[ma * 256 + mp + 1]       * r01 + f01 * g01);
    sum += c1 * e0 * Smat[(ma + 1) * 256 + mp]     * (Qmat[(ma + 1) * 256 + mp]     * r10 + f10 * g10);
    sum += c1 * e1 * Smat[(ma + 1) * 256 + mp + 1] * (Qmat[(ma + 1) * 256 + mp + 1] * r11 + f11 * g11);
    if (ti < tj) sum *= 2.f;
    __syncthreads();           // done reading tiles; reuse lds for reduction
    lds[tid] = sum;
    __syncthreads();
    for (int s = 128; s > 0; s >>= 1) {
        if (tid < s) lds[tid] += lds[tid + s];
        __syncthreads();
    }
    if (tid == 0) partial[b * 36 + idx] = lds[0];
}

// ---------------- final: nrm, pv, g1/g2, output second half ----------------
__global__ __launch_bounds__(256) void k_fin(const float* __restrict__ state,
                                             const float* __restrict__ W2,
                                             float* __restrict__ ws,
                                             float* __restrict__ out) {
    int b = blockIdx.x;
    int tid = threadIdx.x;
    __shared__ float vs[128], g1[256], g2[256], red[256];
    __shared__ float snrm;
    if (tid < 128) vs[tid] = state[(16 + b) * 128 + tid];
    red[tid] = (tid < 36) ? ws[OFF_PART + b * 36 + tid] : 0.f;
    __syncthreads();
    for (int s = 128; s > 0; s >>= 1) {
        if (tid < s) red[tid] += red[tid + s];
        __syncthreads();
    }
    if (tid == 0) snrm = sqrtf(fmaxf(2.f * red[0], 0.f));
    __syncthreads();

    const float* ptb = ws + OFF_PT + b * 32768;
    int m = tid;
    float pv = 0.f;
    for (int j = 0; j < 128; ++j)
        pv += ptb[j * 256 + m] * vs[j];   // coalesced
    float cc  = ws[OFF_C  + b * 256 + m];
    float uvm = ws[OFF_UV + b * 256 + m];
    float avm = ws[OFF_AV + b * 256 + m];
    g1[m] = cc * pv  * uvm;
    g2[m] = cc * avm * uvm;
    __syncthreads();

    if (tid < 128) {
        int i = tid;
        float raw = 0.f;
        for (int mm = 0; mm < 256; ++mm)
            raw += W2[mm * 128 + i] * g1[mm] + ptb[i * 256 + mm] * g2[mm];
        float vn = ws[OFF_VN + b];
        float a  = -0.5f * raw / ((snrm + 1e-6f) * (vn + 1e-6f));
        out[(16 + b) * 128 + i] = a - 0.1f * state[b * 128 + i];
    }
}

extern "C" void kernel_launch(void* const* d_in, const int* in_sizes, int n_in,
                              void* d_out, int out_size, void* d_ws, size_t ws_size,
                              hipStream_t stream) {
    (void)in_sizes; (void)n_in; (void)out_size; (void)ws_size;
    const float* t     = (const float*)d_in[0];
    const float* state = (const float*)d_in[1];
    const float* x0    = (const float*)d_in[2];
    const float* x1    = (const float*)d_in[3];
    const float* W1    = (const float*)d_in[4];
    const float* b1    = (const float*)d_in[5];
    const float* W2    = (const float*)d_in[6];
    // b2 (d_in[7]) cancels in the Jacobian — unused.
    float* out = (float*)d_out;
    float* ws  = (float*)d_ws;

    // W1T [256][128], W2T [128][256]
    k_transpose<<<dim3(8, 4), 256, 0, stream>>>(W1, ws + OFF_W1T, 128, 256);
    k_transpose<<<dim3(4, 8), 256, 0, stream>>>(W2, ws + OFF_W2T, 256, 128);
    // S = W1^T W1 (gram of W1T rows), Q = W2 W2^T (gram of W2 rows)
    k_gram<<<dim3(8, 8), 256, 0, stream>>>(ws + OFF_W1T, ws + OFF_S);
    k_gram<<<dim3(8, 8), 256, 0, stream>>>(W2, ws + OFF_Q);
    // per-sample scalars/vectors (+ first-half output)
    k_prep<<<16, 256, 0, stream>>>(t, state, x0, x1, W1, b1, ws, out);
    // P (transposed) per sample
    k_pmat<<<dim3(4, 8, 16), 256, 0, stream>>>(ws + OFF_S, ws + OFF_D, W2, ws + OFF_PT);
    // Frobenius-norm partials
    k_fnorm<<<dim3(36, 16), 256, 0, stream>>>(ws + OFF_PT, ws + OFF_W2T, ws + OFF_S,
                                              ws + OFF_Q, ws + OFF_C, ws + OFF_PART);
    // final contraction + second-half output
    k_fin<<<16, 256, 0, stream>>>(state, W2, ws, out);
}

// Round 2
// 126.900 us; speedup vs baseline: 1.1459x; 1.1459x over previous
//
#include <hip/hip_runtime.h>
#include <math.h>

// Problem constants: N=128 features, H=256 hidden, B=16 batch.
//
// Analytic collapse of the reference:
//   S = W1^T W1  [256x256] (symmetric), Q = W2 W2^T [256x256] (symmetric)
//   per sample: d = 1-tanh^2(h), c = -2 z d,  P = S diag(d) W2  [256x128]
//   dG[i,j,k] = T[i,j,k] + T[j,i,k],  T[i,j,k] = sum_m W2[m,i] c_m P[m,j] W1[k,m]
//   ||dG||_F^2 = 2 sum_{m,m'} c_m c_m' S[m,m'] ( Q[m,m'] R[m,m'] + M[m,m'] M[m',m] )
//        R = P P^T, M = P W2^T
//   Gamma contraction collapses to 0.5*( W2^T (c .* Pv .* Uv) + P^T (c .* W2v .* Uv) )

// ws layout (float offsets)
static constexpr int OFF_W2T  = 0;            // [128][256]
static constexpr int OFF_S    = 32768;        // [256][256]
static constexpr int OFF_Q    = 98304;        // [256][256]
static constexpr int OFF_D    = 163840;       // [16][256]
static constexpr int OFF_C    = 167936;       // [16][256]
static constexpr int OFF_UV   = 172032;       // [16][256]
static constexpr int OFF_AV   = 176128;       // [16][256]
static constexpr int OFF_VN   = 180224;       // [16]
static constexpr int OFF_PART = 180240;       // [16][36]
static constexpr int OFF_PT   = 180992;       // [16][128][256]  PT[b][j][m] = P[b][m][j]
static constexpr int OFF_PN   = 705536;       // [16][256][128]  Pn[b][m][j] = P[b][m][j]
// total ~= 1229824 floats ~= 4.9 MB

// =====================================================================
// Stage 1 (one kernel, 176 blocks x 256 thr):
//   blocks   0..63 : S = W1^T W1          (gram over columns of W1)
//   blocks  64..127: Q = W2 W2^T          (gram over rows of W2)
//   blocks 128..159: W2T transpose
//   blocks 160..175: per-sample prep (x, tanh, d, c, Uv, W2v, ||v||, out rows 0..15)
// =====================================================================
__global__ __launch_bounds__(256) void k_stage1(const float* __restrict__ tptr,
                                                const float* __restrict__ state,
                                                const float* __restrict__ x0,
                                                const float* __restrict__ x1,
                                                const float* __restrict__ W1,
                                                const float* __restrict__ b1,
                                                const float* __restrict__ W2,
                                                float* __restrict__ ws,
                                                float* __restrict__ out) {
    __shared__ __align__(16) float smem[2 * 32 * 34];
    int blk = blockIdx.x;
    int tid = threadIdx.x;

    if (blk < 64) {
        // ---- S[m,n] = sum_k W1[k,m] W1[k,n], W1 is [128][256] ----
        float* Ai = smem;            // [32][34] : [k][m]
        float* Aj = smem + 1088;
        int m0 = (blk >> 3) * 32, n0 = (blk & 7) * 32;
        int lx = tid & 31, lr = tid >> 5;
        int tx = tid & 15, ty = tid >> 4;
        float a00 = 0, a01 = 0, a10 = 0, a11 = 0;
        for (int kc = 0; kc < 128; kc += 32) {
            #pragma unroll
            for (int i = 0; i < 4; ++i) {
                int k = lr + 8 * i;
                Ai[k * 34 + lx] = W1[(kc + k) * 256 + m0 + lx];
                Aj[k * 34 + lx] = W1[(kc + k) * 256 + n0 + lx];
            }
            __syncthreads();
            #pragma unroll
            for (int k = 0; k < 32; ++k) {
                float2 a = *(const float2*)&Ai[k * 34 + 2 * ty];
                float2 b = *(const float2*)&Aj[k * 34 + 2 * tx];
                a00 += a.x * b.x; a01 += a.x * b.y;
                a10 += a.y * b.x; a11 += a.y * b.y;
            }
            __syncthreads();
        }
        float* S = ws + OFF_S;
        int m = m0 + 2 * ty, n = n0 + 2 * tx;
        S[m * 256 + n]           = a00;
        S[m * 256 + n + 1]       = a01;
        S[(m + 1) * 256 + n]     = a10;
        S[(m + 1) * 256 + n + 1] = a11;
    } else if (blk < 128) {
        // ---- Q[m,n] = sum_j W2[m,j] W2[n,j], W2 is [256][128] ----
        float* Xi = smem;            // [32][34] : [j][m]
        float* Xj = smem + 1088;
        int bq = blk - 64;
        int m0 = (bq >> 3) * 32, n0 = (bq & 7) * 32;
        int lx = tid & 31, lr = tid >> 5;
        int tx = tid & 15, ty = tid >> 4;
        float a00 = 0, a01 = 0, a10 = 0, a11 = 0;
        for (int kc = 0; kc < 128; kc += 32) {
            #pragma unroll
            for (int i = 0; i < 4; ++i) {
                Xi[lx * 34 + lr + 8 * i] = W2[(m0 + lr + 8 * i) * 128 + kc + lx];
                Xj[lx * 34 + lr + 8 * i] = W2[(n0 + lr + 8 * i) * 128 + kc + lx];
            }
            __syncthreads();
            #pragma unroll
            for (int k = 0; k < 32; ++k) {
                float2 a = *(const float2*)&Xi[k * 34 + 2 * ty];
                float2 b = *(const float2*)&Xj[k * 34 + 2 * tx];
                a00 += a.x * b.x; a01 += a.x * b.y;
                a10 += a.y * b.x; a11 += a.y * b.y;
            }
            __syncthreads();
        }
        float* Q = ws + OFF_Q;
        int m = m0 + 2 * ty, n = n0 + 2 * tx;
        Q[m * 256 + n]           = a00;
        Q[m * 256 + n + 1]       = a01;
        Q[(m + 1) * 256 + n]     = a10;
        Q[(m + 1) * 256 + n + 1] = a11;
    } else if (blk < 160) {
        // ---- W2T[c][r] = W2[r][c]; W2 [256][128] -> W2T [128][256] ----
        float* tile = smem;  // [32][33]
        int b2 = blk - 128;
        int c0 = (b2 & 3) * 32, r0 = (b2 >> 2) * 32;
        int tx = tid & 31, ty = tid >> 5;
        #pragma unroll
        for (int i = 0; i < 32; i += 8)
            tile[(ty + i) * 33 + tx] = W2[(r0 + ty + i) * 128 + c0 + tx];
        __syncthreads();
        float* W2T = ws + OFF_W2T;
        #pragma unroll
        for (int i = 0; i < 32; i += 8)
            W2T[(c0 + ty + i) * 256 + r0 + tx] = tile[tx * 33 + ty + i];
    } else {
        // ---- per-sample prep ----
        int b = blk - 160;
        float* xs  = smem;
        float* vs  = smem + 128;
        float* red = smem + 256;
        float t = tptr[0];
        float w = 4.f * t * (1.f - t);
        if (tid < 128) {
            float dev = state[b * 128 + tid];
            float v   = state[(16 + b) * 128 + tid];
            float xv  = x0[b * 128 + tid] + t * (x1[b * 128 + tid] - x0[b * 128 + tid]) + w * dev;
            xs[tid] = xv;
            vs[tid] = v;
            out[b * 128 + tid] = v;   // first-half output = dev_velocity
            red[tid] = v * v;
        }
        __syncthreads();
        for (int s = 64; s > 0; s >>= 1) {
            if (tid < s) red[tid] += red[tid + s];
            __syncthreads();
        }
        if (tid == 0) ws[OFF_VN + b] = sqrtf(red[0]);

        int m = tid;  // 0..255
        float h = b1[m], uvm = 0.f;
        #pragma unroll 8
        for (int k = 0; k < 128; ++k) {
            float wv = W1[k * 256 + m];    // coalesced
            h   += xs[k] * wv;
            uvm += vs[k] * wv;
        }
        float z  = tanhf(h);
        float dd = 1.f - z * z;
        float cc = -2.f * z * dd;
        // av_m = sum_j W2[m,j] v_j  (per-thread contiguous row, float4)
        const float4* w2r = (const float4*)&W2[m * 128];
        const float4* vs4 = (const float4*)vs;
        float avm = 0.f;
        #pragma unroll 8
        for (int j4 = 0; j4 < 32; ++j4) {
            float4 ww = w2r[j4];
            float4 vv = vs4[j4];
            avm += ww.x * vv.x + ww.y * vv.y + ww.z * vv.z + ww.w * vv.w;
        }
        ws[OFF_D  + b * 256 + m] = dd;
        ws[OFF_C  + b * 256 + m] = cc;
        ws[OFF_UV + b * 256 + m] = uvm;
        ws[OFF_AV + b * 256 + m] = avm;
    }
}

// =====================================================================
// P = S diag(d) W2, per sample. 64-thr blocks, 4x4 per thread, 32x32 tiles.
// Writes PT[b][j][m] and Pn[b][m][j].
// =====================================================================
__global__ __launch_bounds__(64) void k_pmat2(const float* __restrict__ Smat,
                                              const float* __restrict__ dall,
                                              const float* __restrict__ W2,
                                              float* __restrict__ PT,
                                              float* __restrict__ Pn) {
    __shared__ __align__(16) float ST[32 * 36];  // [n][m]
    __shared__ __align__(16) float YT[32 * 36];  // [n][j]
    int b = blockIdx.z, mt = blockIdx.y, jt = blockIdx.x;
    int m0 = mt * 32, j0 = jt * 32;
    const float* dvec = dall + b * 256;
    int tid = threadIdx.x;
    int nr = tid >> 3, l4 = (tid & 7) * 4;   // staging: 8 rows x 8 float4
    int ty = tid >> 3, tx = tid & 7;         // compute: 4m x 4j per thread
    float acc[4][4] = {};
    for (int nc = 0; nc < 256; nc += 32) {
        #pragma unroll
        for (int i = 0; i < 4; ++i) {
            int n = nr + 8 * i;
            // S symmetric: S[m,n] = S[n,m] -> coalesced row reads
            *(float4*)&ST[n * 36 + l4] = *(const float4*)&Smat[(nc + n) * 256 + m0 + l4];
            float dn = dvec[nc + n];
            float4 wv = *(const float4*)&W2[(nc + n) * 128 + j0 + l4];
            wv.x *= dn; wv.y *= dn; wv.z *= dn; wv.w *= dn;
            *(float4*)&YT[n * 36 + l4] = wv;
        }
        __syncthreads();
        #pragma unroll
        for (int n = 0; n < 32; ++n) {
            float4 a  = *(const float4*)&ST[n * 36 + 4 * ty];
            float4 bb = *(const float4*)&YT[n * 36 + 4 * tx];
            float av[4] = {a.x, a.y, a.z, a.w};
            float bv[4] = {bb.x, bb.y, bb.z, bb.w};
            #pragma unroll
            for (int ii = 0; ii < 4; ++ii)
                #pragma unroll
                for (int jj = 0; jj < 4; ++jj)
                    acc[ii][jj] += av[ii] * bv[jj];
        }
        __syncthreads();
    }
    float* ptb = PT + b * 32768;
    float* pnb = Pn + b * 32768;
    #pragma unroll
    for (int jj = 0; jj < 4; ++jj) {
        float4 v = make_float4(acc[0][jj], acc[1][jj], acc[2][jj], acc[3][jj]);
        *(float4*)&ptb[(j0 + 4 * tx + jj) * 256 + m0 + 4 * ty] = v;
    }
    #pragma unroll
    for (int ii = 0; ii < 4; ++ii) {
        float4 v = make_float4(acc[ii][0], acc[ii][1], acc[ii][2], acc[ii][3]);
        *(float4*)&pnb[(m0 + 4 * ty + ii) * 128 + j0 + 4 * tx] = v;
    }
}

// =====================================================================
// Frobenius-norm partials. 64-thr blocks, 4x4 per thread, triangular tiles.
// =====================================================================
__global__ __launch_bounds__(64) void k_fnorm2(const float* __restrict__ PT,
                                               const float* __restrict__ W2T,
                                               const float* __restrict__ Smat,
                                               const float* __restrict__ Qmat,
                                               const float* __restrict__ call,
                                               float* __restrict__ partial) {
    __shared__ __align__(16) float lds[16384];  // 64 KB
    float* PiT = lds;              // [128][32]
    float* PjT = lds + 4096;
    float* WiT = lds + 8192;
    float* WjT = lds + 12288;
    int b = blockIdx.y;
    int idx = blockIdx.x;
    int tj = 0;
    while ((tj + 1) * (tj + 2) / 2 <= idx) ++tj;
    int ti = idx - tj * (tj + 1) / 2;      // ti <= tj
    int mi0 = ti * 32, mj0 = tj * 32;
    int tid = threadIdx.x;
    const float* ptb = PT + b * 32768;
    int jr = tid >> 3, jc4 = (tid & 7) * 4;
    #pragma unroll
    for (int it = 0; it < 16; ++it) {
        int j = jr + 8 * it;
        *(float4*)&PiT[j * 32 + jc4] = *(const float4*)&ptb[j * 256 + mi0 + jc4];
        *(float4*)&PjT[j * 32 + jc4] = *(const float4*)&ptb[j * 256 + mj0 + jc4];
        *(float4*)&WiT[j * 32 + jc4] = *(const float4*)&W2T[j * 256 + mi0 + jc4];
        *(float4*)&WjT[j * 32 + jc4] = *(const float4*)&W2T[j * 256 + mj0 + jc4];
    }
    __syncthreads();
    int ty = tid >> 3, tx = tid & 7;
    float r[4][4] = {}, f[4][4] = {}, g[4][4] = {};
    #pragma unroll 4
    for (int j = 0; j < 128; ++j) {
        float4 pi4 = *(const float4*)&PiT[j * 32 + 4 * ty];
        float4 pj4 = *(const float4*)&PjT[j * 32 + 4 * tx];
        float4 wi4 = *(const float4*)&WiT[j * 32 + 4 * ty];
        float4 wj4 = *(const float4*)&WjT[j * 32 + 4 * tx];
        float pi[4] = {pi4.x, pi4.y, pi4.z, pi4.w};
        float pj[4] = {pj4.x, pj4.y, pj4.z, pj4.w};
        float wi[4] = {wi4.x, wi4.y, wi4.z, wi4.w};
        float wj[4] = {wj4.x, wj4.y, wj4.z, wj4.w};
        #pragma unroll
        for (int ii = 0; ii < 4; ++ii)
            #pragma unroll
            for (int jj = 0; jj < 4; ++jj) {
                r[ii][jj] += pi[ii] * pj[jj];   // R[mi,mj]
                f[ii][jj] += pi[ii] * wj[jj];   // M[mi,mj]
                g[ii][jj] += pj[jj] * wi[ii];   // M[mj,mi]
            }
    }
    const float* cb = call + b * 256;
    float sum = 0.f;
    int mi = mi0 + 4 * ty, mj = mj0 + 4 * tx;
    float4 ce4 = *(const float4*)&cb[mj];
    float ce[4] = {ce4.x, ce4.y, ce4.z, ce4.w};
    #pragma unroll
    for (int ii = 0; ii < 4; ++ii) {
        float ci = cb[mi + ii];
        float4 S4 = *(const float4*)&Smat[(mi + ii) * 256 + mj];
        float4 Q4 = *(const float4*)&Qmat[(mi + ii) * 256 + mj];
        float Sv[4] = {S4.x, S4.y, S4.z, S4.w};
        float Qv[4] = {Q4.x, Q4.y, Q4.z, Q4.w};
        #pragma unroll
        for (int jj = 0; jj < 4; ++jj)
            sum += ci * ce[jj] * Sv[jj] * (Qv[jj] * r[ii][jj] + f[ii][jj] * g[ii][jj]);
    }
    if (ti < tj) sum *= 2.f;
    #pragma unroll
    for (int off = 32; off > 0; off >>= 1)
        sum += __shfl_down(sum, off);
    if (tid == 0) partial[b * 36 + idx] = sum;
}

// =====================================================================
// Final: nrm, pv, g1/g2, second-half output. 16 blocks x 256 thr.
// =====================================================================
__global__ __launch_bounds__(256) void k_fin2(const float* __restrict__ state,
                                              const float* __restrict__ W2,
                                              float* __restrict__ ws,
                                              float* __restrict__ out) {
    int b = blockIdx.x;
    int tid = threadIdx.x;
    __shared__ float vs[128], g1[256], g2[256], red[256];
    __shared__ float snrm;
    if (tid < 128) vs[tid] = state[(16 + b) * 128 + tid];
    red[tid] = (tid < 36) ? ws[OFF_PART + b * 36 + tid] : 0.f;
    __syncthreads();
    for (int s = 128; s > 0; s >>= 1) {
        if (tid < s) red[tid] += red[tid + s];
        __syncthreads();
    }
    if (tid == 0) snrm = sqrtf(fmaxf(2.f * red[0], 0.f));
    __syncthreads();

    const float* ptb = ws + OFF_PT + b * 32768;
    const float* pnb = ws + OFF_PN + b * 32768;
    int m = tid;
    float pv = 0.f;
    #pragma unroll 8
    for (int j = 0; j < 128; ++j)
        pv += ptb[j * 256 + m] * vs[j];   // coalesced over m
    float cc  = ws[OFF_C  + b * 256 + m];
    float uvm = ws[OFF_UV + b * 256 + m];
    float avm = ws[OFF_AV + b * 256 + m];
    g1[m] = cc * pv  * uvm;
    g2[m] = cc * avm * uvm;
    __syncthreads();

    // raw_i = sum_mm W2[mm,i] g1[mm] + Pn[mm,i] g2[mm]; split mm over 2 half-threads
    int i = tid & 127, half = tid >> 7;
    int mmlo = half * 128;
    float raw = 0.f;
    #pragma unroll 8
    for (int mm = mmlo; mm < mmlo + 128; ++mm)
        raw += W2[mm * 128 + i] * g1[mm] + pnb[mm * 128 + i] * g2[mm];  // both coalesced
    red[tid] = raw;
    __syncthreads();
    if (tid < 128) {
        float rawt = red[tid] + red[tid + 128];
        float vn = ws[OFF_VN + b];
        float a  = -0.5f * rawt / ((snrm + 1e-6f) * (vn + 1e-6f));
        out[(16 + b) * 128 + tid] = a - 0.1f * state[b * 128 + tid];
    }
}

extern "C" void kernel_launch(void* const* d_in, const int* in_sizes, int n_in,
                              void* d_out, int out_size, void* d_ws, size_t ws_size,
                              hipStream_t stream) {
    (void)in_sizes; (void)n_in; (void)out_size; (void)ws_size;
    const float* t     = (const float*)d_in[0];
    const float* state = (const float*)d_in[1];
    const float* x0    = (const float*)d_in[2];
    const float* x1    = (const float*)d_in[3];
    const float* W1    = (const float*)d_in[4];
    const float* b1    = (const float*)d_in[5];
    const float* W2    = (const float*)d_in[6];
    // b2 cancels in the Jacobian — unused.
    float* out = (float*)d_out;
    float* ws  = (float*)d_ws;

    k_stage1<<<176, 256, 0, stream>>>(t, state, x0, x1, W1, b1, W2, ws, out);
    k_pmat2<<<dim3(4, 8, 16), 64, 0, stream>>>(ws + OFF_S, ws + OFF_D, W2,
                                               ws + OFF_PT, ws + OFF_PN);
    k_fnorm2<<<dim3(36, 16), 64, 0, stream>>>(ws + OFF_PT, ws + OFF_W2T, ws + OFF_S,
                                              ws + OFF_Q, ws + OFF_C, ws + OFF_PART);
    k_fin2<<<16, 256, 0, stream>>>(state, W2, ws, out);
}